// Round 10
// baseline (86.559 us; speedup 1.0000x reference)
//
#include <hip/hip_runtime.h>
#include <hip/hip_bf16.h>

#define BSZ 4096
#define NSZ 8192
#define DD  128
#define TILE 128

typedef __attribute__((ext_vector_type(8))) short bf16x8;
typedef __attribute__((ext_vector_type(4))) float f32x4;

typedef __attribute__((address_space(3))) unsigned int lds_u32;
typedef const __attribute__((address_space(1))) unsigned int glb_u32;

// ---------------- Kernel 1: normalize rows of reps=[zjs; zis] -> bf16 ----------------
__global__ __launch_bounds__(256)
void norm_kernel(const float* __restrict__ zis,
                 const float* __restrict__ zjs,
                 __hip_bfloat16* __restrict__ rn) {
    const int row  = blockIdx.x * 4 + (threadIdx.x >> 6);
    const int lane = threadIdx.x & 63;
    const float* src = (row < BSZ) ? (zjs + (size_t)row * DD)
                                   : (zis + (size_t)(row - BSZ) * DD);
    float2 v = *(const float2*)(src + lane * 2);
    float ss = v.x * v.x + v.y * v.y;
    #pragma unroll
    for (int off = 32; off; off >>= 1) ss += __shfl_xor(ss, off);
    float inv = 1.0f / fmaxf(sqrtf(ss), 1e-8f);
    __hip_bfloat16 a = __float2bfloat16(v.x * inv);
    __hip_bfloat16 b = __float2bfloat16(v.y * inv);
    ushort2 pk;
    pk.x = *(const ushort*)&a;
    pk.y = *(const ushort*)&b;
    *(ushort2*)(rn + (size_t)row * DD + lane * 2) = pk;
}

// ---------------- Kernel 2: triangular deep-loop fused sim GEMM (R5 structure) -------
// grid (8, 64): q = blockIdx.x (d-chunk), bi = blockIdx.y (row tile).
// Block (q,bi) processes tiles bj=(bi+d)&63 for d = q*4..q*4+3; blocks with
// bi<32 && (bi&7)==q additionally process d=32. Covers each unordered tile pair
// exactly once (d=0 diag self-masked; d=1..31 unique; d=32 once via bi<32).
// Per tile: row-sums -> registers (flushed once to rowp[q]); col-sums (transpose
// contribution) -> kg-butterfly shfl, per-wave store to colp[(d-1)*2+wm].
// LDS double-buffered B staging via global_load_lds with pre-swizzled source.
__global__ __launch_bounds__(256, 2)
void sim_lse_kernel(const __hip_bfloat16* __restrict__ rn,
                    float* __restrict__ partials,   // [72][NSZ]: 8 row + 64 col slabs
                    float* __restrict__ pos) {
    __shared__ ushort Bt[2][TILE * DD];   // 2 x 32 KB

    const int q   = blockIdx.x;
    const int bi  = blockIdx.y;
    const int tid = threadIdx.x;
    const int wid  = tid >> 6;
    const int lane = tid & 63;
    const int l15  = lane & 15;
    const int kg   = lane >> 4;        // 0..3
    const int wm   = wid >> 1;         // 0..1 row half
    const int wn   = wid & 1;          // 0..1 col half

    const int nt = (bi < 32 && (bi & 7) == q) ? 5 : 4;

    // ---- A fragments: 64 rows (this wave's wm half), in registers ----
    const char* abase = (const char*)rn + (size_t)(bi * TILE + wm * 64 + l15) * 256;
    bf16x8 af[4][4];
    #pragma unroll
    for (int mf = 0; mf < 4; ++mf)
        #pragma unroll
        for (int kk = 0; kk < 4; ++kk)
            af[mf][kk] = *(const bf16x8*)(abase + mf * 16 * 256 + kk * 64 + kg * 16);

    // ---- stage tile 0 (pre-swizzled global source, linear LDS dest) ----
    {
        const char* gbase = (const char*)rn + (size_t)(((bi + q * 4) & 63)) * TILE * 256;
        #pragma unroll
        for (int j = 0; j < 8; ++j) {
            int cs  = (wid * 8 + j) * 64 + lane;
            int gsc = cs ^ ((cs >> 4) & 7);
            __builtin_amdgcn_global_load_lds((glb_u32*)(gbase + (size_t)gsc * 16),
                                             (lds_u32*)(&Bt[0][0] + (wid * 8 + j) * 512),
                                             16, 0, 0);
        }
    }
    __syncthreads();

    float rsum[4][4] = {};

    for (int t = 0; t < nt; ++t) {
        const int d  = (t < 4) ? q * 4 + t : 32;
        const int bj = (bi + d) & 63;

        // prefetch next tile into the other buffer
        if (t + 1 < nt) {
            const int dn  = (t + 1 < 4) ? q * 4 + t + 1 : 32;
            const int bjn = (bi + dn) & 63;
            const char* gbase = (const char*)rn + (size_t)bjn * TILE * 256;
            ushort* dst = &Bt[(t + 1) & 1][0];
            #pragma unroll
            for (int j = 0; j < 8; ++j) {
                int cs  = (wid * 8 + j) * 64 + lane;
                int gsc = cs ^ ((cs >> 4) & 7);
                __builtin_amdgcn_global_load_lds((glb_u32*)(gbase + (size_t)gsc * 16),
                                                 (lds_u32*)(dst + (wid * 8 + j) * 512),
                                                 16, 0, 0);
            }
        }

        // ---- MFMA: 64 rows x 64 cols per wave, K=128 ----
        f32x4 acc[4][4] = {};
        const char* Bb = (const char*)&Bt[t & 1][0];
        #pragma unroll
        for (int kk = 0; kk < 4; ++kk) {
            const int kb = kk * 64 + kg * 16;
            bf16x8 bfr[4];
            #pragma unroll
            for (int nf = 0; nf < 4; ++nf) {
                int cR = wn * 64 + nf * 16 + l15;
                int o = cR * 256 + kb;
                bfr[nf] = *(const bf16x8*)(Bb + (o ^ ((cR & 7) << 4)));
            }
            #pragma unroll
            for (int mf = 0; mf < 4; ++mf)
                #pragma unroll
                for (int nf = 0; nf < 4; ++nf)
                    acc[mf][nf] = __builtin_amdgcn_mfma_f32_16x16x32_bf16(
                        af[mf][kk], bfr[nf], acc[mf][nf], 0, 0, 0);
        }

        // ---- epilogue: exp once; row sums (regs) + col sums (this tile) ----
        const bool dglb = (d == 0)  && (wm == wn);
        const bool pglb = (d == 32) && (wm == wn);
        float csum[4] = {0.f, 0.f, 0.f, 0.f};
        #pragma unroll
        for (int mf = 0; mf < 4; ++mf) {
            #pragma unroll
            for (int nf = 0; nf < 4; ++nf) {
                #pragma unroll
                for (int reg = 0; reg < 4; ++reg) {
                    float s = acc[mf][nf][reg];
                    bool hit = (mf == nf) && (kg * 4 + reg == l15);
                    if (pglb && hit) {
                        pos[bi * TILE + wm * 64 + mf * 16 + l15] = s;
                        pos[(bi + 32) * TILE + wm * 64 + mf * 16 + l15] = s;
                    }
                    float p = __expf(s * 10.0f);
                    if (dglb && hit) p = 0.0f;
                    rsum[mf][reg] += p;
                    csum[nf] += p;
                }
            }
        }

        // col-sum store (transpose contribution); diagonal tile contributes rows only
        if (d != 0) {
            float* cp = partials + (size_t)(8 + (d - 1) * 2 + wm) * NSZ + bj * TILE;
            #pragma unroll
            for (int nf = 0; nf < 4; ++nf) {
                float v = csum[nf];
                v += __shfl_xor(v, 16);
                v += __shfl_xor(v, 32);
                if (kg == 0) cp[wn * 64 + nf * 16 + l15] = v;
            }
        }

        __syncthreads();   // drains vmcnt (stage t+1 done) + protects buffers
    }

    // ---- row-sum reduce: across l15 lanes, then across wn via LDS; store rowp[q] ----
    #pragma unroll
    for (int mf = 0; mf < 4; ++mf)
        #pragma unroll
        for (int reg = 0; reg < 4; ++reg) {
            float v = rsum[mf][reg];
            v += __shfl_xor(v, 1);
            v += __shfl_xor(v, 2);
            v += __shfl_xor(v, 4);
            v += __shfl_xor(v, 8);
            rsum[mf][reg] = v;   // valid on l15==0 lanes
        }

    float* red = (float*)&Bt[0][0];
    if (wn == 1 && l15 == 0) {
        #pragma unroll
        for (int mf = 0; mf < 4; ++mf)
            #pragma unroll
            for (int reg = 0; reg < 4; ++reg)
                red[wm * 64 + mf * 16 + kg * 4 + reg] = rsum[mf][reg];
    }
    __syncthreads();
    if (wn == 0 && l15 == 0) {
        #pragma unroll
        for (int mf = 0; mf < 4; ++mf)
            #pragma unroll
            for (int reg = 0; reg < 4; ++reg) {
                int lr = wm * 64 + mf * 16 + kg * 4 + reg;
                partials[(size_t)q * NSZ + bi * TILE + lr] = rsum[mf][reg] + red[lr];
            }
    }
}

// ---------------- Kernel 3: final scalar reduction over 72 slabs ----------------
__global__ __launch_bounds__(1024)
void reduce_kernel(const float* __restrict__ partials,
                   const float* __restrict__ pos,
                   float* __restrict__ out) {
    int tid = threadIdx.x;  // 1024; 8 rows each
    int base = tid * 8;
    float se[8] = {0.f, 0.f, 0.f, 0.f, 0.f, 0.f, 0.f, 0.f};
    // slabs 0..69: rowp (0..7) + colp d=1..31 (8..69), valid for all rows
    for (int gr = 0; gr < 70; ++gr) {
        const float* p = partials + (size_t)gr * NSZ + base;
        float4 a = *(const float4*)(p);
        float4 b = *(const float4*)(p + 4);
        se[0] += a.x; se[1] += a.y; se[2] += a.z; se[3] += a.w;
        se[4] += b.x; se[5] += b.y; se[6] += b.z; se[7] += b.w;
    }
    // slabs 70,71: colp d=32 -- written only for rows >= BSZ (bj >= 32)
    if (base >= BSZ) {
        #pragma unroll
        for (int gr = 70; gr < 72; ++gr) {
            const float* p = partials + (size_t)gr * NSZ + base;
            float4 a = *(const float4*)(p);
            float4 b = *(const float4*)(p + 4);
            se[0] += a.x; se[1] += a.y; se[2] += a.z; se[3] += a.w;
            se[4] += b.x; se[5] += b.y; se[6] += b.z; se[7] += b.w;
        }
    }
    float ce = 0.f, pt = 0.f;
    #pragma unroll
    for (int h = 0; h < 2; ++h) {
        float4 p4 = *(const float4*)(pos + base + h * 4);
        const float* pp = (const float*)&p4;
        #pragma unroll
        for (int qq = 0; qq < 4; ++qq) {
            float s = se[h * 4 + qq];
            ce += __logf(s) - pp[qq] * 10.0f;
            pt += __expf(pp[qq] * 10.0f) / s;
        }
    }
    #pragma unroll
    for (int off = 32; off; off >>= 1) {
        ce += __shfl_xor(ce, off);
        pt += __shfl_xor(pt, off);
    }
    __shared__ float lce[16], lpt[16];
    if ((tid & 63) == 0) { lce[tid >> 6] = ce; lpt[tid >> 6] = pt; }
    __syncthreads();
    if (tid == 0) {
        float CE = 0.f, PT = 0.f;
        #pragma unroll
        for (int w = 0; w < 16; ++w) { CE += lce[w]; PT += lpt[w]; }
        float loss = CE / (float)NSZ + 1.0f
                   - PT * ((float)BSZ / ((float)NSZ * (float)(NSZ - 1)));
        out[0] = loss;
    }
}

extern "C" void kernel_launch(void* const* d_in, const int* in_sizes, int n_in,
                              void* d_out, int out_size, void* d_ws, size_t ws_size,
                              hipStream_t stream) {
    const float* zis = (const float*)d_in[0];
    const float* zjs = (const float*)d_in[1];
    float* out = (float*)d_out;

    char* ws = (char*)d_ws;
    __hip_bfloat16* rn = (__hip_bfloat16*)ws;                         // 2 MB
    float* partials = (float*)(ws + 2 * 1024 * 1024);                 // 72*32KB = 2.25 MB
    float* pos      = (float*)(ws + 2 * 1024 * 1024 + 72 * NSZ * 4);  // 32 KB

    norm_kernel<<<NSZ / 4, 256, 0, stream>>>(zis, zjs, rn);

    dim3 grid(8, 64);
    sim_lse_kernel<<<grid, 256, 0, stream>>>(rn, partials, pos);

    reduce_kernel<<<1, 1024, 0, stream>>>(partials, pos, out);
}

// Round 11
// 46.216 us; speedup vs baseline: 1.8729x; 1.8729x over previous
//
#include <hip/hip_runtime.h>
#include <hip/hip_bf16.h>

#define BSZ 4096
#define NSZ 8192
#define DD  128
#define TILE 128
#define GROUPS 8
#define TPB 8     // col-tiles per block

typedef __attribute__((ext_vector_type(8))) short bf16x8;
typedef __attribute__((ext_vector_type(4))) float f32x4;

typedef __attribute__((address_space(3))) unsigned int lds_u32;
typedef const __attribute__((address_space(1))) unsigned int glb_u32;

// ---------------- Kernel 1: normalize rows of reps=[zjs; zis] -> bf16 ----------------
__global__ __launch_bounds__(256)
void norm_kernel(const float* __restrict__ zis,
                 const float* __restrict__ zjs,
                 __hip_bfloat16* __restrict__ rn) {
    const int row  = blockIdx.x * 4 + (threadIdx.x >> 6);
    const int lane = threadIdx.x & 63;
    const float* src = (row < BSZ) ? (zjs + (size_t)row * DD)
                                   : (zis + (size_t)(row - BSZ) * DD);
    float2 v = *(const float2*)(src + lane * 2);
    float ss = v.x * v.x + v.y * v.y;
    #pragma unroll
    for (int off = 32; off; off >>= 1) ss += __shfl_xor(ss, off);
    float inv = 1.0f / fmaxf(sqrtf(ss), 1e-8f);
    __hip_bfloat16 a = __float2bfloat16(v.x * inv);
    __hip_bfloat16 b = __float2bfloat16(v.y * inv);
    ushort2 pk;
    pk.x = *(const ushort*)&a;
    pk.y = *(const ushort*)&b;
    *(ushort2*)(rn + (size_t)row * DD + lane * 2) = pk;
}

// ---------------- Kernel 2: deep-loop fused sim GEMM, pressure-fitted waves ---------
// grid (GROUPS, 64): bi = blockIdx.y (128-row tile), g = blockIdx.x; block loops
// over bj = g*TPB .. g*TPB+7 with double-buffered LDS B staging (global_load_lds,
// pre-swizzled source). 512 threads = 8 waves (wm=0..3 x wn=0..1); each wave owns
// a 32x64 sub-tile -> live set ~100 VGPR (af 32 + acc 32 + bfr 16 + rsum 8), fits
// under the allocator's observed 128 budget: no spills, no af reloads (the
// R2/R7-R10 failure mode). Row sums in registers across all 8 tiles; per-wave
// disjoint rows -> direct partials stores, no atomics, no memset.
__global__ __launch_bounds__(512)
void sim_lse_kernel(const __hip_bfloat16* __restrict__ rn,
                    float* __restrict__ partials,   // [16][NSZ]
                    float* __restrict__ pos) {
    __shared__ ushort Bt[2][TILE * DD];   // 2 x 32 KB

    const int g   = blockIdx.x;
    const int bi  = blockIdx.y;
    const int tid = threadIdx.x;
    const int wid  = tid >> 6;         // 0..7
    const int lane = tid & 63;
    const int l15  = lane & 15;
    const int kg   = lane >> 4;        // 0..3
    const int wm   = wid >> 1;         // 0..3 row quarter (32 rows)
    const int wn   = wid & 1;          // 0..1 col half (64 cols)

    // ---- A fragments: this wave's 32 rows, in registers (~32 VGPR) ----
    const char* abase = (const char*)rn + (size_t)(bi * TILE + wm * 32 + l15) * 256;
    bf16x8 af[2][4];
    #pragma unroll
    for (int mf = 0; mf < 2; ++mf)
        #pragma unroll
        for (int kk = 0; kk < 4; ++kk)
            af[mf][kk] = *(const bf16x8*)(abase + mf * 16 * 256 + kk * 64 + kg * 16);

    // ---- stage tile 0 (pre-swizzled global source, linear LDS dest) ----
    {
        const char* gbase = (const char*)rn + (size_t)(g * TPB) * TILE * 256;
        #pragma unroll
        for (int j = 0; j < 4; ++j) {
            int cs  = (wid * 4 + j) * 64 + lane;     // chunk index (16B units)
            int gsc = cs ^ ((cs >> 4) & 7);          // swizzled source chunk
            __builtin_amdgcn_global_load_lds((glb_u32*)(gbase + (size_t)gsc * 16),
                                             (lds_u32*)(&Bt[0][0] + (wid * 4 + j) * 512),
                                             16, 0, 0);
        }
    }
    __syncthreads();

    float rsum[2][4] = {};
    const int bjp = (bi + 32) & 63;
    const int nfd = (wm & 1) * 2;      // diag/pos nf base: nf == nfd + mf
    const bool wdiag = (wn == (wm >> 1));

    for (int t = 0; t < TPB; ++t) {
        const int bj = g * TPB + t;

        // prefetch next tile into the other buffer
        if (t + 1 < TPB) {
            const char* gbase = (const char*)rn + (size_t)(bj + 1) * TILE * 256;
            ushort* dst = &Bt[(t + 1) & 1][0];
            #pragma unroll
            for (int j = 0; j < 4; ++j) {
                int cs  = (wid * 4 + j) * 64 + lane;
                int gsc = cs ^ ((cs >> 4) & 7);
                __builtin_amdgcn_global_load_lds((glb_u32*)(gbase + (size_t)gsc * 16),
                                                 (lds_u32*)(dst + (wid * 4 + j) * 512),
                                                 16, 0, 0);
            }
        }

        // ---- MFMA: 32 rows x 64 cols per wave, K=128 ----
        f32x4 acc[2][4] = {};
        const char* Bb = (const char*)&Bt[t & 1][0];
        #pragma unroll
        for (int kk = 0; kk < 4; ++kk) {
            const int kb = kk * 64 + kg * 16;
            bf16x8 bfr[4];
            #pragma unroll
            for (int nf = 0; nf < 4; ++nf) {
                int cR = wn * 64 + nf * 16 + l15;
                int o = cR * 256 + kb;
                bfr[nf] = *(const bf16x8*)(Bb + (o ^ ((cR & 7) << 4)));
            }
            #pragma unroll
            for (int mf = 0; mf < 2; ++mf)
                #pragma unroll
                for (int nf = 0; nf < 4; ++nf)
                    acc[mf][nf] = __builtin_amdgcn_mfma_f32_16x16x32_bf16(
                        af[mf][kk], bfr[nf], acc[mf][nf], 0, 0, 0);
        }

        // ---- epilogue (register-only): exp + rsum accumulate; rare fixups ----
        const bool dglb = (bj == bi)  && wdiag;
        const bool pglb = (bj == bjp) && wdiag;
        #pragma unroll
        for (int mf = 0; mf < 2; ++mf) {
            #pragma unroll
            for (int nf = 0; nf < 4; ++nf) {
                #pragma unroll
                for (int reg = 0; reg < 4; ++reg) {
                    float s = acc[mf][nf][reg];
                    bool hit = (nf == nfd + mf) && (kg * 4 + reg == l15);
                    if (pglb && hit)
                        pos[bi * TILE + wm * 32 + mf * 16 + l15] = s;
                    float p = __expf(s * 10.0f);
                    if (dglb && hit) p = 0.0f;
                    rsum[mf][reg] += p;
                }
            }
        }

        __syncthreads();   // drains vmcnt (stage t+1 done) + protects buffers
    }

    // ---- row-sum reduce across the 16 l15-lanes; direct store (disjoint slabs) ----
    #pragma unroll
    for (int mf = 0; mf < 2; ++mf)
        #pragma unroll
        for (int reg = 0; reg < 4; ++reg) {
            float v = rsum[mf][reg];
            v += __shfl_xor(v, 1);
            v += __shfl_xor(v, 2);
            v += __shfl_xor(v, 4);
            v += __shfl_xor(v, 8);
            if (l15 == 0)
                partials[(size_t)(g * 2 + wn) * NSZ
                         + bi * TILE + wm * 32 + mf * 16 + kg * 4 + reg] = v;
        }
}

// ---------------- Kernel 3: final scalar reduction over 16 slabs ----------------
__global__ __launch_bounds__(1024)
void reduce_kernel(const float* __restrict__ partials,
                   const float* __restrict__ pos,
                   float* __restrict__ out) {
    int tid = threadIdx.x;  // 1024; 8 rows each
    int base = tid * 8;
    float se[8] = {0.f, 0.f, 0.f, 0.f, 0.f, 0.f, 0.f, 0.f};
    #pragma unroll
    for (int gr = 0; gr < 2 * GROUPS; ++gr) {
        const float* p = partials + (size_t)gr * NSZ + base;
        float4 a = *(const float4*)(p);
        float4 b = *(const float4*)(p + 4);
        se[0] += a.x; se[1] += a.y; se[2] += a.z; se[3] += a.w;
        se[4] += b.x; se[5] += b.y; se[6] += b.z; se[7] += b.w;
    }
    float ce = 0.f, pt = 0.f;
    #pragma unroll
    for (int h = 0; h < 2; ++h) {
        float4 p4 = *(const float4*)(pos + base + h * 4);
        const float* pp = (const float*)&p4;
        #pragma unroll
        for (int q = 0; q < 4; ++q) {
            float s = se[h * 4 + q];
            ce += __logf(s) - pp[q] * 10.0f;
            pt += __expf(pp[q] * 10.0f) / s;
        }
    }
    #pragma unroll
    for (int off = 32; off; off >>= 1) {
        ce += __shfl_xor(ce, off);
        pt += __shfl_xor(pt, off);
    }
    __shared__ float lce[16], lpt[16];
    if ((tid & 63) == 0) { lce[tid >> 6] = ce; lpt[tid >> 6] = pt; }
    __syncthreads();
    if (tid == 0) {
        float CE = 0.f, PT = 0.f;
        #pragma unroll
        for (int w = 0; w < 16; ++w) { CE += lce[w]; PT += lpt[w]; }
        float loss = CE / (float)NSZ + 1.0f
                   - PT * ((float)BSZ / ((float)NSZ * (float)(NSZ - 1)));
        out[0] = loss;
    }
}

extern "C" void kernel_launch(void* const* d_in, const int* in_sizes, int n_in,
                              void* d_out, int out_size, void* d_ws, size_t ws_size,
                              hipStream_t stream) {
    const float* zis = (const float*)d_in[0];
    const float* zjs = (const float*)d_in[1];
    float* out = (float*)d_out;

    char* ws = (char*)d_ws;
    __hip_bfloat16* rn = (__hip_bfloat16*)ws;                       // 2 MB
    float* partials = (float*)(ws + 2 * 1024 * 1024);               // 512 KB
    float* pos      = (float*)(ws + 2 * 1024 * 1024 + 512 * 1024);  // 32 KB

    norm_kernel<<<NSZ / 4, 256, 0, stream>>>(zis, zjs, rn);

    dim3 grid(GROUPS, 64);
    sim_lse_kernel<<<grid, 512, 0, stream>>>(rn, partials, pos);

    reduce_kernel<<<1, 1024, 0, stream>>>(partials, pos, out);
}

// Round 12
// 41.738 us; speedup vs baseline: 2.0739x; 1.1073x over previous
//
#include <hip/hip_runtime.h>
#include <hip/hip_bf16.h>

#define BSZ 4096
#define NSZ 8192
#define DD  128
#define TILE 128
#define GROUPS 8
#define TPB 8     // col-tiles per block

typedef __attribute__((ext_vector_type(8))) short bf16x8;
typedef __attribute__((ext_vector_type(4))) float f32x4;

typedef __attribute__((address_space(3))) unsigned int lds_u32;
typedef const __attribute__((address_space(1))) unsigned int glb_u32;

// ---------------- Kernel 1: normalize rows of reps=[zjs; zis] -> bf16 ----------------
__global__ __launch_bounds__(256)
void norm_kernel(const float* __restrict__ zis,
                 const float* __restrict__ zjs,
                 __hip_bfloat16* __restrict__ rn) {
    const int row  = blockIdx.x * 4 + (threadIdx.x >> 6);
    const int lane = threadIdx.x & 63;
    const float* src = (row < BSZ) ? (zjs + (size_t)row * DD)
                                   : (zis + (size_t)(row - BSZ) * DD);
    float2 v = *(const float2*)(src + lane * 2);
    float ss = v.x * v.x + v.y * v.y;
    #pragma unroll
    for (int off = 32; off; off >>= 1) ss += __shfl_xor(ss, off);
    float inv = 1.0f / fmaxf(sqrtf(ss), 1e-8f);
    __hip_bfloat16 a = __float2bfloat16(v.x * inv);
    __hip_bfloat16 b = __float2bfloat16(v.y * inv);
    ushort2 pk;
    pk.x = *(const ushort*)&a;
    pk.y = *(const ushort*)&b;
    *(ushort2*)(rn + (size_t)row * DD + lane * 2) = pk;
}

// ---------------- Kernel 2: both-operands-in-LDS fused sim GEMM (m97 structure) -----
// grid (GROUPS, 64): bi = blockIdx.y (128-row tile), g = blockIdx.x; block loops
// over bj = g*TPB .. g*TPB+7. A-tile (32KB) staged to LDS once; B-tile (32KB)
// single-buffered, staged per tile (global_load_lds, pre-swizzled source).
// 512 threads = 8 waves (wm 0..3 x wn 0..1), wave tile 32x64. ALL MFMA operands
// come from LDS via per-kk ds_read (8-reg lifetime) -- no tile-lifetime register
// residency for the allocator to defeat (the R7-R11 failure mode). 64KB LDS ->
// 2 blocks/CU; each block's exposed stage drain is covered by the other block.
// Row sums in registers across all 8 tiles; direct partials stores, no atomics.
__global__ __launch_bounds__(512, 4)
void sim_lse_kernel(const __hip_bfloat16* __restrict__ rn,
                    float* __restrict__ partials,   // [16][NSZ]
                    float* __restrict__ pos) {
    __shared__ ushort As[TILE * DD];   // 32 KB, XOR-swizzled
    __shared__ ushort Bs[TILE * DD];   // 32 KB, XOR-swizzled

    const int g   = blockIdx.x;
    const int bi  = blockIdx.y;
    const int tid = threadIdx.x;
    const int wid  = tid >> 6;         // 0..7
    const int lane = tid & 63;
    const int l15  = lane & 15;
    const int kg   = lane >> 4;        // 0..3
    const int wm   = wid >> 1;         // 0..3 row quarter (32 rows)
    const int wn   = wid & 1;          // 0..1 col half (64 cols)

    // ---- stage A tile (once) and B tile 0; linear LDS dest, pre-swizzled source ----
    {
        const char* ga = (const char*)rn + (size_t)bi * TILE * 256;
        const char* gb = (const char*)rn + (size_t)(g * TPB) * TILE * 256;
        #pragma unroll
        for (int j = 0; j < 4; ++j) {
            int cs  = (wid * 4 + j) * 64 + lane;     // chunk index (16B units)
            int gsc = cs ^ ((cs >> 4) & 7);          // swizzled source chunk
            __builtin_amdgcn_global_load_lds((glb_u32*)(ga + (size_t)gsc * 16),
                                             (lds_u32*)(As + (wid * 4 + j) * 512),
                                             16, 0, 0);
            __builtin_amdgcn_global_load_lds((glb_u32*)(gb + (size_t)gsc * 16),
                                             (lds_u32*)(Bs + (wid * 4 + j) * 512),
                                             16, 0, 0);
        }
    }
    __syncthreads();   // drains vmcnt: As + Bs ready

    float rsum[2][4] = {};
    const int bjp = (bi + 32) & 63;
    const int nfd = (wm & 1) * 2;      // diag/pos nf base: nf == nfd + mf
    const bool wdiag = (wn == (wm >> 1));
    const char* Ab = (const char*)As;
    const char* Bb = (const char*)Bs;

    for (int t = 0; t < TPB; ++t) {
        const int bj = g * TPB + t;

        // ---- MFMA: 32 rows x 64 cols per wave, K=128; operands ds_read per kk ----
        f32x4 acc[2][4] = {};
        #pragma unroll
        for (int kk = 0; kk < 4; ++kk) {
            const int kb = kk * 64 + kg * 16;
            bf16x8 afr[2];
            #pragma unroll
            for (int mf = 0; mf < 2; ++mf) {
                int rR = wm * 32 + mf * 16 + l15;
                int o = rR * 256 + kb;
                afr[mf] = *(const bf16x8*)(Ab + (o ^ ((rR & 7) << 4)));
            }
            bf16x8 bfr[4];
            #pragma unroll
            for (int nf = 0; nf < 4; ++nf) {
                int cR = wn * 64 + nf * 16 + l15;
                int o = cR * 256 + kb;
                bfr[nf] = *(const bf16x8*)(Bb + (o ^ ((cR & 7) << 4)));
            }
            #pragma unroll
            for (int mf = 0; mf < 2; ++mf)
                #pragma unroll
                for (int nf = 0; nf < 4; ++nf)
                    acc[mf][nf] = __builtin_amdgcn_mfma_f32_16x16x32_bf16(
                        afr[mf], bfr[nf], acc[mf][nf], 0, 0, 0);
        }

        // ---- epilogue (register-only): exp + rsum accumulate; rare fixups ----
        const bool dglb = (bj == bi)  && wdiag;
        const bool pglb = (bj == bjp) && wdiag;
        #pragma unroll
        for (int mf = 0; mf < 2; ++mf) {
            #pragma unroll
            for (int nf = 0; nf < 4; ++nf) {
                #pragma unroll
                for (int reg = 0; reg < 4; ++reg) {
                    float s = acc[mf][nf][reg];
                    bool hit = (nf == nfd + mf) && (kg * 4 + reg == l15);
                    if (pglb && hit)
                        pos[bi * TILE + wm * 32 + mf * 16 + l15] = s;
                    float p = __expf(s * 10.0f);
                    if (dglb && hit) p = 0.0f;
                    rsum[mf][reg] += p;
                }
            }
        }

        __syncthreads();   // all waves done reading Bs

        // ---- stage next B tile into the (single) buffer; drain before compute ----
        if (t + 1 < TPB) {
            const char* gb = (const char*)rn + (size_t)(bj + 1) * TILE * 256;
            #pragma unroll
            for (int j = 0; j < 4; ++j) {
                int cs  = (wid * 4 + j) * 64 + lane;
                int gsc = cs ^ ((cs >> 4) & 7);
                __builtin_amdgcn_global_load_lds((glb_u32*)(gb + (size_t)gsc * 16),
                                                 (lds_u32*)(Bs + (wid * 4 + j) * 512),
                                                 16, 0, 0);
            }
            __syncthreads();   // drains vmcnt: Bs ready (other block covers this gap)
        }
    }

    // ---- row-sum reduce across the 16 l15-lanes; direct store (disjoint slabs) ----
    #pragma unroll
    for (int mf = 0; mf < 2; ++mf)
        #pragma unroll
        for (int reg = 0; reg < 4; ++reg) {
            float v = rsum[mf][reg];
            v += __shfl_xor(v, 1);
            v += __shfl_xor(v, 2);
            v += __shfl_xor(v, 4);
            v += __shfl_xor(v, 8);
            if (l15 == 0)
                partials[(size_t)(g * 2 + wn) * NSZ
                         + bi * TILE + wm * 32 + mf * 16 + kg * 4 + reg] = v;
        }
}

// ---------------- Kernel 3: final scalar reduction over 16 slabs ----------------
__global__ __launch_bounds__(1024)
void reduce_kernel(const float* __restrict__ partials,
                   const float* __restrict__ pos,
                   float* __restrict__ out) {
    int tid = threadIdx.x;  // 1024; 8 rows each
    int base = tid * 8;
    float se[8] = {0.f, 0.f, 0.f, 0.f, 0.f, 0.f, 0.f, 0.f};
    #pragma unroll
    for (int gr = 0; gr < 2 * GROUPS; ++gr) {
        const float* p = partials + (size_t)gr * NSZ + base;
        float4 a = *(const float4*)(p);
        float4 b = *(const float4*)(p + 4);
        se[0] += a.x; se[1] += a.y; se[2] += a.z; se[3] += a.w;
        se[4] += b.x; se[5] += b.y; se[6] += b.z; se[7] += b.w;
    }
    float ce = 0.f, pt = 0.f;
    #pragma unroll
    for (int h = 0; h < 2; ++h) {
        float4 p4 = *(const float4*)(pos + base + h * 4);
        const float* pp = (const float*)&p4;
        #pragma unroll
        for (int q = 0; q < 4; ++q) {
            float s = se[h * 4 + q];
            ce += __logf(s) - pp[q] * 10.0f;
            pt += __expf(pp[q] * 10.0f) / s;
        }
    }
    #pragma unroll
    for (int off = 32; off; off >>= 1) {
        ce += __shfl_xor(ce, off);
        pt += __shfl_xor(pt, off);
    }
    __shared__ float lce[16], lpt[16];
    if ((tid & 63) == 0) { lce[tid >> 6] = ce; lpt[tid >> 6] = pt; }
    __syncthreads();
    if (tid == 0) {
        float CE = 0.f, PT = 0.f;
        #pragma unroll
        for (int w = 0; w < 16; ++w) { CE += lce[w]; PT += lpt[w]; }
        float loss = CE / (float)NSZ + 1.0f
                   - PT * ((float)BSZ / ((float)NSZ * (float)(NSZ - 1)));
        out[0] = loss;
    }
}

extern "C" void kernel_launch(void* const* d_in, const int* in_sizes, int n_in,
                              void* d_out, int out_size, void* d_ws, size_t ws_size,
                              hipStream_t stream) {
    const float* zis = (const float*)d_in[0];
    const float* zjs = (const float*)d_in[1];
    float* out = (float*)d_out;

    char* ws = (char*)d_ws;
    __hip_bfloat16* rn = (__hip_bfloat16*)ws;                       // 2 MB
    float* partials = (float*)(ws + 2 * 1024 * 1024);               // 512 KB
    float* pos      = (float*)(ws + 2 * 1024 * 1024 + 512 * 1024);  // 32 KB

    norm_kernel<<<NSZ / 4, 256, 0, stream>>>(zis, zjs, rn);

    dim3 grid(GROUPS, 64);
    sim_lse_kernel<<<grid, 512, 0, stream>>>(rn, partials, pos);

    reduce_kernel<<<1, 1024, 0, stream>>>(partials, pos, out);
}